// Round 6
// baseline (1164.950 us; speedup 1.0000x reference)
//
#include <hip/hip_runtime.h>
#include <hip/hip_bf16.h>

#define NTOK 2048

typedef __attribute__((ext_vector_type(8))) short short8_t;
typedef __attribute__((ext_vector_type(4))) float f32x4;

__device__ __forceinline__ float bu2f(unsigned short u) {
  unsigned int x = ((unsigned int)u) << 16; float f; __builtin_memcpy(&f, &x, 4); return f;
}
__device__ __forceinline__ unsigned short f2bu(float f) {
  __hip_bfloat16 h = __float2bfloat16(f);
  unsigned short u; __builtin_memcpy(&u, &h, 2); return u;
}
__device__ __forceinline__ float sigm(float x) { return 1.0f / (1.0f + __expf(-x)); }
__device__ __forceinline__ uint4 pack8(const float* v) {
  unsigned short u[8];
#pragma unroll
  for (int i = 0; i < 8; ++i) u[i] = f2bu(v[i]);
  uint4 r; __builtin_memcpy(&r, u, 16); return r;
}

// ------------------------------------------------------------------
// K1: fused prep (weights transpose+fold, dual LN) + windowed pair bias.
//   DIAGNOSTIC: body repeated `reps` times (idempotent).
// ------------------------------------------------------------------
__global__ __launch_bounds__(256) void prep_bias_kernel(
    const float* __restrict__ act, const float* __restrict__ cond,
    const float* __restrict__ lns_q, const float* __restrict__ lns_k,
    const float* __restrict__ WgQ, const float* __restrict__ WsQ,
    const float* __restrict__ WgK, const float* __restrict__ WsK,
    const float* __restrict__ Wq, const float* __restrict__ Wk,
    const float* __restrict__ Wv, const float* __restrict__ Wg,
    const float* __restrict__ Wgs, const float* __restrict__ Wo,
    const float* __restrict__ pair, const float* __restrict__ lnz_w,
    const float* __restrict__ Wb,
    unsigned short* __restrict__ wt_all, unsigned short* __restrict__ xn_b,
    unsigned short* __restrict__ sn_b, unsigned short* __restrict__ cond_b,
    unsigned short* __restrict__ bias_h, int reps)
{
  const int tid = threadIdx.x;
  const int bid = blockIdx.x;
  __shared__ float tile[32][36];
  __shared__ float lw[16], wb[16][4];

  for (int rep = 0; rep < reps; ++rep) {
    asm volatile("" ::: "memory");
    if (bid < 1024) {
      // ---- windowed pair bias ----
      if (tid < 16) lw[tid] = lnz_w[tid];
      if (tid < 64) wb[tid >> 2][tid & 3] = Wb[tid];
      __syncthreads();
      const int idx = bid * 256 + tid;
      const int i = idx >> 7, jw = idx & 127;
      const int j = ((i >> 5) << 5) - 48 + jw;
      float bo[4] = {-1e9f, -1e9f, -1e9f, -1e9f};
      if (j >= 0 && j < NTOK) {
        const float4* p = (const float4*)(pair + ((size_t)i * NTOK + j) * 16);
        float4 z0 = p[0], z1 = p[1], z2 = p[2], z3 = p[3];
        float z[16] = {z0.x, z0.y, z0.z, z0.w, z1.x, z1.y, z1.z, z1.w,
                       z2.x, z2.y, z2.z, z2.w, z3.x, z3.y, z3.z, z3.w};
        float s = 0.f, ss = 0.f;
#pragma unroll
        for (int c = 0; c < 16; ++c) { s += z[c]; ss += z[c]*z[c]; }
        const float m = s * (1.f/16.f), v = ss * (1.f/16.f) - m*m;
        const float r = rsqrtf(v + 1e-5f);
        bo[0] = bo[1] = bo[2] = bo[3] = 0.f;
#pragma unroll
        for (int c = 0; c < 16; ++c) {
          const float zn = (z[c] - m) * r * lw[c];
          bo[0] += zn * wb[c][0]; bo[1] += zn * wb[c][1];
          bo[2] += zn * wb[c][2]; bo[3] += zn * wb[c][3];
        }
      }
#pragma unroll
      for (int h = 0; h < 4; ++h)
        bias_h[(size_t)h * (NTOK * 128) + idx] = f2bu(bo[h]);
    } else if (bid < 1184) {
      // ---- weight transpose + fold ----
      const float* srcs[10] = {WgQ, WsQ, WgK, WsK, Wq, Wk, Wv, Wg, Wgs, Wo};
      const int wbk = bid - 1024;
      const int wi = wbk >> 4, tt = wbk & 15;
      const int tr = tt >> 2, tc = tt & 3;
      const float* W = srcs[wi];
      const int rr = tid >> 3, c4 = (tid & 7) << 2;
      const int k = tr * 32 + rr;
      float4 v = *(const float4*)(W + (size_t)k * 128 + tc * 32 + c4);
      float f = 1.0f;
      if (wi < 2) f = lns_q[k];
      else if (wi < 4) f = lns_k[k];
      tile[rr][c4 + 0] = v.x * f; tile[rr][c4 + 1] = v.y * f;
      tile[rr][c4 + 2] = v.z * f; tile[rr][c4 + 3] = v.w * f;
      __syncthreads();
      ushort4 o;
      o.x = f2bu(tile[c4 + 0][rr]); o.y = f2bu(tile[c4 + 1][rr]);
      o.z = f2bu(tile[c4 + 2][rr]); o.w = f2bu(tile[c4 + 3][rr]);
      *(ushort4*)(wt_all + (size_t)wi * 16384 + (size_t)(tc * 32 + rr) * 128 + tr * 32 + c4) = o;
    } else {
      // ---- dual LN ----
      const int rb = bid - 1184;
      const int r = rb * 32 + (tid >> 3);
      const int c0 = (tid & 7) << 4;
      float xv[16], cv[16];
      const float4* ap = (const float4*)(act + (size_t)r * 128 + c0);
      const float4* cp = (const float4*)(cond + (size_t)r * 128 + c0);
#pragma unroll
      for (int i = 0; i < 4; ++i) {
        float4 a4 = ap[i], b4 = cp[i];
        xv[4*i+0]=a4.x; xv[4*i+1]=a4.y; xv[4*i+2]=a4.z; xv[4*i+3]=a4.w;
        cv[4*i+0]=b4.x; cv[4*i+1]=b4.y; cv[4*i+2]=b4.z; cv[4*i+3]=b4.w;
      }
      float sx=0.f, sxx=0.f, sc=0.f, scc=0.f;
#pragma unroll
      for (int i = 0; i < 16; ++i) { sx+=xv[i]; sxx+=xv[i]*xv[i]; sc+=cv[i]; scc+=cv[i]*cv[i]; }
#pragma unroll
      for (int m = 1; m < 8; m <<= 1) {
        sx += __shfl_xor(sx, m); sxx += __shfl_xor(sxx, m);
        sc += __shfl_xor(sc, m); scc += __shfl_xor(scc, m);
      }
      const float mx = sx * (1.f/128.f), vx = sxx*(1.f/128.f) - mx*mx;
      const float mc = sc * (1.f/128.f), vc = scc*(1.f/128.f) - mc*mc;
      const float rx = rsqrtf(vx + 1e-5f), rc = rsqrtf(vc + 1e-5f);
      float xo[16], so[16];
#pragma unroll
      for (int i = 0; i < 16; ++i) { xo[i] = (xv[i]-mx)*rx; so[i] = (cv[i]-mc)*rc; }
      uint4* xp = (uint4*)(xn_b + (size_t)r*128 + c0);
      xp[0] = pack8(xo); xp[1] = pack8(xo+8);
      uint4* sp = (uint4*)(sn_b + (size_t)r*128 + c0);
      sp[0] = pack8(so); sp[1] = pack8(so+8);
      uint4* cpo = (uint4*)(cond_b + (size_t)r*128 + c0);
      cpo[0] = pack8(cv); cpo[1] = pack8(cv+8);
    }
    __syncthreads();
  }
}

// ---- shared GEMM helpers (XOR-swizzled LDS, 8-elem groups) ----
__device__ __forceinline__ void stage_A32(unsigned short* a_lds, const unsigned short* src,
                                          int row0, int tid) {
  const int r = tid >> 3, c0 = (tid & 7) << 4;
  const uint4* g = (const uint4*)(src + (size_t)(row0 + r) * 128 + c0);
  uint4 v0 = g[0], v1 = g[1];
  const int x = (r & 7) << 3;
  *(uint4*)&a_lds[r * 128 + (c0 ^ x)] = v0;
  *(uint4*)&a_lds[r * 128 + ((c0 + 8) ^ x)] = v1;
}
__device__ __forceinline__ void stage_W(unsigned short* w_lds, const unsigned short* src, int tid) {
  const int n = tid >> 1;
  const int kb = (tid & 1) << 6;
  const int x = (n & 7) << 3;
  const uint4* g = (const uint4*)(src + (size_t)n * 128 + kb);
#pragma unroll
  for (int i = 0; i < 8; ++i) {
    uint4 v = g[i];
    *(uint4*)&w_lds[n * 128 + ((kb + i * 8) ^ x)] = v;
  }
}
__device__ __forceinline__ void gemm32(const unsigned short* a_lds, const unsigned short* w_lds,
                                       int lm, int kg, int wv, f32x4 acc[2][2]) {
  const int xa = (lm & 7) << 3;
#pragma unroll
  for (int ks = 0; ks < 4; ++ks) {
    const int ko = ks * 32 + kg * 8;
    short8_t av[2], bv[2];
#pragma unroll
    for (int mi = 0; mi < 2; ++mi)
      av[mi] = *(const short8_t*)&a_lds[(mi * 16 + lm) * 128 + (ko ^ xa)];
#pragma unroll
    for (int ni = 0; ni < 2; ++ni) {
      const int n = (wv * 2 + ni) * 16 + lm;
      bv[ni] = *(const short8_t*)&w_lds[n * 128 + (ko ^ xa)];
    }
#pragma unroll
    for (int mi = 0; mi < 2; ++mi)
#pragma unroll
      for (int ni = 0; ni < 2; ++ni)
        acc[mi][ni] = __builtin_amdgcn_mfma_f32_16x16x32_bf16(av[mi], bv[ni], acc[mi][ni], 0, 0, 0);
  }
}

// ------------------------------------------------------------------
// K2: fused projections. DIAGNOSTIC: body repeated `reps` times.
// ------------------------------------------------------------------
__global__ __launch_bounds__(256) void proj_kernel(
    const unsigned short* __restrict__ wt_all, const unsigned short* __restrict__ xn_b,
    const unsigned short* __restrict__ sn_b, const unsigned short* __restrict__ cond_b,
    const float* __restrict__ bgate_q, const float* __restrict__ bgate_k,
    const float* __restrict__ bq, const float* __restrict__ bgs,
    unsigned short* __restrict__ q_b, unsigned short* __restrict__ k_b,
    unsigned short* __restrict__ v_b, unsigned short* __restrict__ gsig_b,
    unsigned short* __restrict__ gs_b, int reps)
{
  __shared__ unsigned short a_lds[32 * 128];
  __shared__ unsigned short a2_lds[32 * 128];
  __shared__ unsigned short w_lds[128 * 128];
  __shared__ unsigned short stash[32 * 136];
  __shared__ unsigned short xn_lds[32 * 136];
  const int tid = threadIdx.x;
  const int br = blockIdx.x / 64;
  const int rt = blockIdx.x % 64;
  const int row0 = rt * 32;
  const int l = tid & 63, wv = tid >> 6;
  const int lm = l & 15, kg = l >> 4;

  for (int rep = 0; rep < reps; ++rep) {
    asm volatile("" ::: "memory");
    if (br == 2) {
      stage_A32(a_lds, cond_b, row0, tid);
      stage_W(w_lds, wt_all + (size_t)8 * 16384, tid);
      __syncthreads();
      f32x4 acc[2][2] = {};
      gemm32(a_lds, w_lds, lm, kg, wv, acc);
      float bgv[2];
#pragma unroll
      for (int ni = 0; ni < 2; ++ni) bgv[ni] = bgs[(wv * 2 + ni) * 16 + lm];
#pragma unroll
      for (int mi = 0; mi < 2; ++mi)
#pragma unroll
        for (int ni = 0; ni < 2; ++ni)
#pragma unroll
          for (int r = 0; r < 4; ++r) {
            const int rl = mi * 16 + kg * 4 + r;
            const int n = (wv * 2 + ni) * 16 + lm;
            gs_b[(size_t)(row0 + rl) * 128 + n] = f2bu(sigm(acc[mi][ni][r] + bgv[ni]));
          }
    } else {
      const int w0 = (br == 0) ? 0 : 2;
      stage_A32(a_lds, sn_b, row0, tid);
      {
        const int r = tid >> 3, c0 = (tid & 7) << 4;
        const uint4* g = (const uint4*)(xn_b + (size_t)(row0 + r) * 128 + c0);
        uint4 v0 = g[0], v1 = g[1];
        *(uint4*)&xn_lds[r * 136 + c0] = v0;
        *(uint4*)&xn_lds[r * 136 + c0 + 8] = v1;
      }
      stage_W(w_lds, wt_all + (size_t)w0 * 16384, tid);
      __syncthreads();
      f32x4 acc[2][2] = {};
      gemm32(a_lds, w_lds, lm, kg, wv, acc);
#pragma unroll
      for (int mi = 0; mi < 2; ++mi)
#pragma unroll
        for (int ni = 0; ni < 2; ++ni)
#pragma unroll
          for (int r = 0; r < 4; ++r) {
            const int rl = mi * 16 + kg * 4 + r;
            const int n = (wv * 2 + ni) * 16 + lm;
            stash[rl * 136 + n] = f2bu(acc[mi][ni][r]);
          }
      __syncthreads();
      stage_W(w_lds, wt_all + (size_t)(w0 + 1) * 16384, tid);
      __syncthreads();
      f32x4 acc2[2][2] = {};
      gemm32(a_lds, w_lds, lm, kg, wv, acc2);
      {
        const float* bg = (br == 0) ? bgate_q : bgate_k;
        float bgv[2];
#pragma unroll
        for (int ni = 0; ni < 2; ++ni) bgv[ni] = bg[(wv * 2 + ni) * 16 + lm];
#pragma unroll
        for (int mi = 0; mi < 2; ++mi)
#pragma unroll
          for (int ni = 0; ni < 2; ++ni)
#pragma unroll
            for (int r = 0; r < 4; ++r) {
              const int rl = mi * 16 + kg * 4 + r;
              const int n = (wv * 2 + ni) * 16 + lm;
              const float gate = sigm(bu2f(stash[rl * 136 + n]) + bgv[ni]);
              const float a = gate * bu2f(xn_lds[rl * 136 + n]) + acc2[mi][ni][r];
              a2_lds[rl * 128 + (n ^ ((rl & 7) << 3))] = f2bu(a);
            }
      }
      __syncthreads();
      stage_W(w_lds, wt_all + (size_t)((br == 0) ? 4 : 5) * 16384, tid);
      __syncthreads();
      f32x4 acc3[2][2] = {};
      gemm32(a2_lds, w_lds, lm, kg, wv, acc3);
      {
        const float scale = 0.17677669529663687f;
        float bqv[2] = {0.f, 0.f};
        if (br == 0) {
#pragma unroll
          for (int ni = 0; ni < 2; ++ni) bqv[ni] = bq[(wv * 2 + ni) * 16 + lm];
        }
        unsigned short* dst = (br == 0) ? q_b : k_b;
#pragma unroll
        for (int mi = 0; mi < 2; ++mi)
#pragma unroll
          for (int ni = 0; ni < 2; ++ni)
#pragma unroll
            for (int r = 0; r < 4; ++r) {
              const int rl = mi * 16 + kg * 4 + r;
              const int n = (wv * 2 + ni) * 16 + lm;
              float v = acc3[mi][ni][r];
              if (br == 0) v = (v + bqv[ni]) * scale;
              dst[(size_t)(row0 + rl) * 128 + n] = f2bu(v);
            }
      }
      __syncthreads();
      stage_W(w_lds, wt_all + (size_t)((br == 0) ? 7 : 6) * 16384, tid);
      __syncthreads();
      f32x4 acc4[2][2] = {};
      gemm32(a2_lds, w_lds, lm, kg, wv, acc4);
      {
        unsigned short* dst = (br == 0) ? gsig_b : v_b;
#pragma unroll
        for (int mi = 0; mi < 2; ++mi)
#pragma unroll
          for (int ni = 0; ni < 2; ++ni)
#pragma unroll
            for (int r = 0; r < 4; ++r) {
              const int rl = mi * 16 + kg * 4 + r;
              const int n = (wv * 2 + ni) * 16 + lm;
              float v = acc4[mi][ni][r];
              if (br == 0) v = sigm(v);
              dst[(size_t)(row0 + rl) * 128 + n] = f2bu(v);
            }
      }
    }
    __syncthreads();
  }
}

// ------------------------------------------------------------------
// K3: fused attention + output projection. DIAGNOSTIC: repeated `reps`.
// ------------------------------------------------------------------
__global__ __launch_bounds__(512) void attn_out_kernel(
    const unsigned short* __restrict__ q_b, const unsigned short* __restrict__ k_b,
    const unsigned short* __restrict__ v_b, const unsigned short* __restrict__ gsig_b,
    const unsigned short* __restrict__ gs_b, const unsigned short* __restrict__ bias_h,
    const unsigned short* __restrict__ wt_all, float* __restrict__ out, int reps)
{
  __shared__ unsigned short kw[16384];            // pass: K (2 heads); final: Wo
  __shared__ unsigned short vt[2][32 * 128];
  __shared__ unsigned short p_lds[2][32 * 128];
  __shared__ unsigned short q_lds[2][32 * 64];
  __shared__ unsigned short bias_lds[2][32 * 136];
  __shared__ float mxlds[2][4][32];
  __shared__ float smlds[2][4][32];
  __shared__ f32x4 op[2][16][64];
  __shared__ unsigned short o_lds[32 * 128];

  const int tid = threadIdx.x;
  const int b = blockIdx.x;
  const int j0 = b * 32 - 48;
  const int t = tid & 255;
  const int hh = tid >> 8;
  const int l = t & 63, wv = t >> 6;
  const int lm = l & 15, kg = l >> 4;

  for (int rep = 0; rep < reps; ++rep) {
    asm volatile("" ::: "memory");
    for (int hp = 0; hp < 2; ++hp) {
      const int h = hp * 2 + hh;
      unsigned short* k_lds = kw + hh * 8192;
      { // Q stage
        const int r = t >> 3, c0 = (t & 7) << 2;
        ushort4 v = *(const ushort4*)(q_b + (size_t)(b * 32 + r) * 128 + h * 32 + c0);
        *(ushort4*)&q_lds[hh][r * 64 + (c0 ^ ((r & 7) << 3))] = v;
      }
      { // bias stage
        const int r = t >> 3, c0 = (t & 7) << 4;
        const uint4* g = (const uint4*)(bias_h + (size_t)h * (NTOK * 128) + (size_t)(b * 32 + r) * 128 + c0);
        uint4 v0 = g[0], v1 = g[1];
        *(uint4*)&bias_lds[hh][r * 136 + c0] = v0;
        *(uint4*)&bias_lds[hh][r * 136 + c0 + 8] = v1;
      }
      { // K + V stage (V transposed)
        const int jw = t >> 1, cb = (t & 1) << 4;
        const int j = j0 + jw;
        uint4 kv0 = {0,0,0,0}, kv1 = {0,0,0,0}, vv0 = {0,0,0,0}, vv1 = {0,0,0,0};
        if (j >= 0 && j < NTOK) {
          const uint4* gk = (const uint4*)(k_b + (size_t)j * 128 + h * 32 + cb);
          kv0 = gk[0]; kv1 = gk[1];
          const uint4* gv = (const uint4*)(v_b + (size_t)j * 128 + h * 32 + cb);
          vv0 = gv[0]; vv1 = gv[1];
        }
        const int xk = (jw & 7) << 3;
        *(uint4*)&k_lds[jw * 64 + (cb ^ xk)] = kv0;
        *(uint4*)&k_lds[jw * 64 + ((cb + 8) ^ xk)] = kv1;
        unsigned short tmp[16];
        __builtin_memcpy(tmp, &vv0, 16);
        __builtin_memcpy(tmp + 8, &vv1, 16);
#pragma unroll
        for (int i2 = 0; i2 < 16; ++i2) {
          const int c = cb + i2;
          vt[hh][c * 128 + ((jw & 7) | ((jw & 120) ^ ((c & 7) << 3)))] = tmp[i2];
        }
      }
      __syncthreads();

      // QK^T
      f32x4 sc[2][2] = {};
      {
        const int xa = (lm & 7) << 3;
        short8_t aq[2], bk[2];
#pragma unroll
        for (int mi = 0; mi < 2; ++mi)
          aq[mi] = *(const short8_t*)&q_lds[hh][(mi * 16 + lm) * 64 + ((kg * 8) ^ xa)];
#pragma unroll
        for (int ni = 0; ni < 2; ++ni) {
          const int key = (wv * 2 + ni) * 16 + lm;
          bk[ni] = *(const short8_t*)&k_lds[key * 64 + ((kg * 8) ^ ((key & 7) << 3))];
        }
#pragma unroll
        for (int mi = 0; mi < 2; ++mi)
#pragma unroll
          for (int ni = 0; ni < 2; ++ni)
            sc[mi][ni] = __builtin_amdgcn_mfma_f32_16x16x32_bf16(aq[mi], bk[ni], sc[mi][ni], 0, 0, 0);
      }
      float sv[2][2][4];
#pragma unroll
      for (int mi = 0; mi < 2; ++mi)
#pragma unroll
        for (int ni = 0; ni < 2; ++ni)
#pragma unroll
          for (int r = 0; r < 4; ++r) {
            const int q = mi * 16 + kg * 4 + r;
            const int key = (wv * 2 + ni) * 16 + lm;
            sv[mi][ni][r] = sc[mi][ni][r] + bu2f(bias_lds[hh][q * 136 + key]);
          }
#pragma unroll
      for (int mi = 0; mi < 2; ++mi)
#pragma unroll
        for (int r = 0; r < 4; ++r) {
          float m0 = fmaxf(sv[mi][0][r], sv[mi][1][r]);
#pragma unroll
          for (int msk = 1; msk < 16; msk <<= 1) m0 = fmaxf(m0, __shfl_xor(m0, msk));
          if (lm == 0) mxlds[hh][wv][mi * 16 + kg * 4 + r] = m0;
        }
      __syncthreads();
#pragma unroll
      for (int mi = 0; mi < 2; ++mi)
#pragma unroll
        for (int r = 0; r < 4; ++r) {
          const int q = mi * 16 + kg * 4 + r;
          const float m = fmaxf(fmaxf(mxlds[hh][0][q], mxlds[hh][1][q]),
                                fmaxf(mxlds[hh][2][q], mxlds[hh][3][q]));
          float s = 0.f;
#pragma unroll
          for (int ni = 0; ni < 2; ++ni) {
            const float e = __expf(sv[mi][ni][r] - m);
            const int key = (wv * 2 + ni) * 16 + lm;
            p_lds[hh][q * 128 + ((key & 7) | ((key & 120) ^ ((q & 7) << 3)))] = f2bu(e);
            s += e;
          }
#pragma unroll
          for (int msk = 1; msk < 16; msk <<= 1) s += __shfl_xor(s, msk);
          if (lm == 0) smlds[hh][wv][q] = s;
        }
      // PV: wave-local 32 keys
      f32x4 oacc[2][2] = {};
      {
        const int key0 = wv * 32 + kg * 8;
        short8_t pa[2], vbf[2];
#pragma unroll
        for (int mi = 0; mi < 2; ++mi) {
          const int q = mi * 16 + lm;
          pa[mi] = *(const short8_t*)&p_lds[hh][q * 128 + (key0 ^ ((q & 7) << 3))];
        }
#pragma unroll
        for (int ct = 0; ct < 2; ++ct) {
          const int c = ct * 16 + lm;
          vbf[ct] = *(const short8_t*)&vt[hh][c * 128 + (key0 ^ ((c & 7) << 3))];
        }
#pragma unroll
        for (int mi = 0; mi < 2; ++mi)
#pragma unroll
          for (int ct = 0; ct < 2; ++ct)
            oacc[mi][ct] = __builtin_amdgcn_mfma_f32_16x16x32_bf16(pa[mi], vbf[ct], oacc[mi][ct], 0, 0, 0);
      }
#pragma unroll
      for (int mi = 0; mi < 2; ++mi)
#pragma unroll
        for (int ct = 0; ct < 2; ++ct)
          op[hh][wv * 4 + mi * 2 + ct][l] = oacc[mi][ct];
      __syncthreads();
      { // reduce partials + gsig gate -> o_lds (swizzled bf16)
        const int q = t >> 3, c0 = (t & 7) << 2;
        const int mt = q >> 4, g = (q >> 2) & 3, r = q & 3;
        const float tot = smlds[hh][0][q] + smlds[hh][1][q] + smlds[hh][2][q] + smlds[hh][3][q];
        const float inv = 1.f / tot;
        ushort4 gg = *(const ushort4*)(gsig_b + (size_t)(b * 32 + q) * 128 + h * 32 + c0);
        unsigned short gga[4] = {gg.x, gg.y, gg.z, gg.w};
#pragma unroll
        for (int i2 = 0; i2 < 4; ++i2) {
          const int c = c0 + i2;
          const int ct = c >> 4, lane2 = g * 16 + (c & 15);
          float s = 0.f;
#pragma unroll
          for (int w2 = 0; w2 < 4; ++w2)
            s += ((const float*)&op[hh][w2 * 4 + mt * 2 + ct][lane2])[r];
          const int gcol = h * 32 + c;
          o_lds[q * 128 + (gcol ^ ((q & 7) << 3))] = f2bu(s * inv * bu2f(gga[i2]));
        }
      }
      __syncthreads();
    }

    // stage Wo into kw (512 threads: 64B each)
    {
      const int n = tid >> 2, kc = (tid & 3) << 5;
      const int x = (n & 7) << 3;
      const uint4* g = (const uint4*)(wt_all + (size_t)9 * 16384 + (size_t)n * 128 + kc);
#pragma unroll
      for (int i = 0; i < 4; ++i) {
        uint4 v = g[i];
        *(uint4*)&kw[n * 128 + ((kc + i * 8) ^ x)] = v;
      }
    }
    __syncthreads();
    // out = gs * (o @ Wo): 8 waves = 2 M-halves x 4 N-quarters
    {
      const int wid = tid >> 6, lane = tid & 63;
      const int lm8 = lane & 15, kg8 = lane >> 4;
      const int mh = wid >> 2, nq = wid & 3;
      f32x4 acc[2] = {};
      const int xa = (lm8 & 7) << 3;
#pragma unroll
      for (int ks = 0; ks < 4; ++ks) {
        const int ko = ks * 32 + kg8 * 8;
        short8_t av = *(const short8_t*)&o_lds[(mh * 16 + lm8) * 128 + (ko ^ xa)];
#pragma unroll
        for (int ni = 0; ni < 2; ++ni) {
          const int n = nq * 32 + ni * 16 + lm8;
          short8_t bv = *(const short8_t*)&kw[n * 128 + (ko ^ ((n & 7) << 3))];
          acc[ni] = __builtin_amdgcn_mfma_f32_16x16x32_bf16(av, bv, acc[ni], 0, 0, 0);
        }
      }
#pragma unroll
      for (int ni = 0; ni < 2; ++ni)
#pragma unroll
        for (int r = 0; r < 4; ++r) {
          const int row = mh * 16 + kg8 * 4 + r;
          const int n = nq * 32 + ni * 16 + lm8;
          const float gsv = bu2f(gs_b[(size_t)(b * 32 + row) * 128 + n]);
          out[(size_t)(b * 32 + row) * 128 + n] = acc[ni][r] * gsv;
        }
    }
    __syncthreads();
  }
}

extern "C" void kernel_launch(void* const* d_in, const int* in_sizes, int n_in,
                              void* d_out, int out_size, void* d_ws, size_t ws_size,
                              hipStream_t stream) {
  const float* act     = (const float*)d_in[0];
  const float* pair    = (const float*)d_in[1];
  const float* cond    = (const float*)d_in[2];
  const float* lns_q   = (const float*)d_in[4];
  const float* Wgate_q = (const float*)d_in[5];
  const float* bgate_q = (const float*)d_in[6];
  const float* Wskip_q = (const float*)d_in[7];
  const float* lns_k   = (const float*)d_in[8];
  const float* Wgate_k = (const float*)d_in[9];
  const float* bgate_k = (const float*)d_in[10];
  const float* Wskip_k = (const float*)d_in[11];
  const float* lnz_w   = (const float*)d_in[12];
  const float* Wq      = (const float*)d_in[13];
  const float* bq      = (const float*)d_in[14];
  const float* Wk      = (const float*)d_in[15];
  const float* Wv      = (const float*)d_in[16];
  const float* Wg      = (const float*)d_in[17];
  const float* Wb      = (const float*)d_in[18];
  const float* Wo      = (const float*)d_in[19];
  const float* Wgs     = (const float*)d_in[20];
  const float* bgs     = (const float*)d_in[21];
  float* out           = (float*)d_out;

  unsigned short* ws = (unsigned short*)d_ws;
  unsigned short* wt_all = ws;                      // 10*16384
  unsigned short* xn_b   = ws + 163840;
  unsigned short* sn_b   = ws + 425984;
  unsigned short* cond_b = ws + 688128;
  unsigned short* q_b    = ws + 950272;
  unsigned short* k_b    = ws + 1212416;
  unsigned short* v_b    = ws + 1474560;
  unsigned short* gsig_b = ws + 1736704;
  unsigned short* gs_b   = ws + 1998848;
  unsigned short* bias_h = ws + 2260992;            // 4*2048*128

  // DIAGNOSTIC ROUND: each kernel repeats its (idempotent) body so its single
  // dispatch exceeds the 155us harness fills and appears in rocprof top-5
  // with counters. Decode: per-kernel time = row_dur / reps.
  hipLaunchKernelGGL(prep_bias_kernel, dim3(1248), dim3(256), 0, stream,
                     act, cond, lns_q, lns_k,
                     Wgate_q, Wskip_q, Wgate_k, Wskip_k,
                     Wq, Wk, Wv, Wg, Wgs, Wo,
                     pair, lnz_w, Wb,
                     wt_all, xn_b, sn_b, cond_b, bias_h, 40);
  hipLaunchKernelGGL(proj_kernel, dim3(192), dim3(256), 0, stream,
                     wt_all, xn_b, sn_b, cond_b,
                     bgate_q, bgate_k, bq, bgs,
                     q_b, k_b, v_b, gsig_b, gs_b, 80);
  hipLaunchKernelGGL(attn_out_kernel, dim3(64), dim3(512), 0, stream,
                     q_b, k_b, v_b, gsig_b, gs_b, bias_h, wt_all, out, 40);
}

// Round 7
// 31.367 us; speedup vs baseline: 37.1393x; 37.1393x over previous
//
#include <hip/hip_runtime.h>
#include <hip/hip_bf16.h>

#define NTOK 2048

typedef __attribute__((ext_vector_type(8))) short short8_t;
typedef __attribute__((ext_vector_type(4))) float f32x4;

__device__ __forceinline__ float bu2f(unsigned short u) {
  unsigned int x = ((unsigned int)u) << 16; float f; __builtin_memcpy(&f, &x, 4); return f;
}
__device__ __forceinline__ unsigned short f2bu(float f) {
  __hip_bfloat16 h = __float2bfloat16(f);
  unsigned short u; __builtin_memcpy(&u, &h, 2); return u;
}
__device__ __forceinline__ float sigm(float x) { return 1.0f / (1.0f + __expf(-x)); }
__device__ __forceinline__ uint4 pack8(const float* v) {
  unsigned short u[8];
#pragma unroll
  for (int i = 0; i < 8; ++i) u[i] = f2bu(v[i]);
  uint4 r; __builtin_memcpy(&r, u, 16); return r;
}

// ------------------------------------------------------------------
// K1: fused prep (weights transpose+fold, dual LN) + windowed pair bias.
//   blocks [0,1024): bias; [1024,1184): weights; [1184,1248): LN
// ------------------------------------------------------------------
__global__ __launch_bounds__(256) void prep_bias_kernel(
    const float* __restrict__ act, const float* __restrict__ cond,
    const float* __restrict__ lns_q, const float* __restrict__ lns_k,
    const float* __restrict__ WgQ, const float* __restrict__ WsQ,
    const float* __restrict__ WgK, const float* __restrict__ WsK,
    const float* __restrict__ Wq, const float* __restrict__ Wk,
    const float* __restrict__ Wv, const float* __restrict__ Wg,
    const float* __restrict__ Wgs, const float* __restrict__ Wo,
    const float* __restrict__ pair, const float* __restrict__ lnz_w,
    const float* __restrict__ Wb,
    unsigned short* __restrict__ wt_all, unsigned short* __restrict__ xn_b,
    unsigned short* __restrict__ sn_b, unsigned short* __restrict__ cond_b,
    unsigned short* __restrict__ bias_h)
{
  const int tid = threadIdx.x;
  const int bid = blockIdx.x;
  __shared__ float tile[32][36];
  __shared__ float lw[16], wb[16][4];

  if (bid < 1024) {
    // ---- windowed pair bias ----
    if (tid < 16) lw[tid] = lnz_w[tid];
    if (tid < 64) wb[tid >> 2][tid & 3] = Wb[tid];
    __syncthreads();
    const int idx = bid * 256 + tid;
    const int i = idx >> 7, jw = idx & 127;
    const int j = ((i >> 5) << 5) - 48 + jw;
    float bo[4] = {-1e9f, -1e9f, -1e9f, -1e9f};
    if (j >= 0 && j < NTOK) {
      const float4* p = (const float4*)(pair + ((size_t)i * NTOK + j) * 16);
      float4 z0 = p[0], z1 = p[1], z2 = p[2], z3 = p[3];
      float z[16] = {z0.x, z0.y, z0.z, z0.w, z1.x, z1.y, z1.z, z1.w,
                     z2.x, z2.y, z2.z, z2.w, z3.x, z3.y, z3.z, z3.w};
      float s = 0.f, ss = 0.f;
#pragma unroll
      for (int c = 0; c < 16; ++c) { s += z[c]; ss += z[c]*z[c]; }
      const float m = s * (1.f/16.f), v = ss * (1.f/16.f) - m*m;
      const float r = rsqrtf(v + 1e-5f);
      bo[0] = bo[1] = bo[2] = bo[3] = 0.f;
#pragma unroll
      for (int c = 0; c < 16; ++c) {
        const float zn = (z[c] - m) * r * lw[c];
        bo[0] += zn * wb[c][0]; bo[1] += zn * wb[c][1];
        bo[2] += zn * wb[c][2]; bo[3] += zn * wb[c][3];
      }
    }
#pragma unroll
    for (int h = 0; h < 4; ++h)
      bias_h[(size_t)h * (NTOK * 128) + idx] = f2bu(bo[h]);
  } else if (bid < 1184) {
    // ---- weight transpose + fold ----
    const float* srcs[10] = {WgQ, WsQ, WgK, WsK, Wq, Wk, Wv, Wg, Wgs, Wo};
    const int wbk = bid - 1024;
    const int wi = wbk >> 4, tt = wbk & 15;
    const int tr = tt >> 2, tc = tt & 3;
    const float* W = srcs[wi];
    const int rr = tid >> 3, c4 = (tid & 7) << 2;
    const int k = tr * 32 + rr;
    float4 v = *(const float4*)(W + (size_t)k * 128 + tc * 32 + c4);
    float f = 1.0f;
    if (wi < 2) f = lns_q[k];
    else if (wi < 4) f = lns_k[k];
    tile[rr][c4 + 0] = v.x * f; tile[rr][c4 + 1] = v.y * f;
    tile[rr][c4 + 2] = v.z * f; tile[rr][c4 + 3] = v.w * f;
    __syncthreads();
    ushort4 o;
    o.x = f2bu(tile[c4 + 0][rr]); o.y = f2bu(tile[c4 + 1][rr]);
    o.z = f2bu(tile[c4 + 2][rr]); o.w = f2bu(tile[c4 + 3][rr]);
    *(ushort4*)(wt_all + (size_t)wi * 16384 + (size_t)(tc * 32 + rr) * 128 + tr * 32 + c4) = o;
  } else {
    // ---- dual LN ----
    const int rb = bid - 1184;
    const int r = rb * 32 + (tid >> 3);
    const int c0 = (tid & 7) << 4;
    float xv[16], cv[16];
    const float4* ap = (const float4*)(act + (size_t)r * 128 + c0);
    const float4* cp = (const float4*)(cond + (size_t)r * 128 + c0);
#pragma unroll
    for (int i = 0; i < 4; ++i) {
      float4 a4 = ap[i], b4 = cp[i];
      xv[4*i+0]=a4.x; xv[4*i+1]=a4.y; xv[4*i+2]=a4.z; xv[4*i+3]=a4.w;
      cv[4*i+0]=b4.x; cv[4*i+1]=b4.y; cv[4*i+2]=b4.z; cv[4*i+3]=b4.w;
    }
    float sx=0.f, sxx=0.f, sc=0.f, scc=0.f;
#pragma unroll
    for (int i = 0; i < 16; ++i) { sx+=xv[i]; sxx+=xv[i]*xv[i]; sc+=cv[i]; scc+=cv[i]*cv[i]; }
#pragma unroll
    for (int m = 1; m < 8; m <<= 1) {
      sx += __shfl_xor(sx, m); sxx += __shfl_xor(sxx, m);
      sc += __shfl_xor(sc, m); scc += __shfl_xor(scc, m);
    }
    const float mx = sx * (1.f/128.f), vx = sxx*(1.f/128.f) - mx*mx;
    const float mc = sc * (1.f/128.f), vc = scc*(1.f/128.f) - mc*mc;
    const float rx = rsqrtf(vx + 1e-5f), rc = rsqrtf(vc + 1e-5f);
    float xo[16], so[16];
#pragma unroll
    for (int i = 0; i < 16; ++i) { xo[i] = (xv[i]-mx)*rx; so[i] = (cv[i]-mc)*rc; }
    uint4* xp = (uint4*)(xn_b + (size_t)r*128 + c0);
    xp[0] = pack8(xo); xp[1] = pack8(xo+8);
    uint4* sp = (uint4*)(sn_b + (size_t)r*128 + c0);
    sp[0] = pack8(so); sp[1] = pack8(so+8);
    uint4* cpo = (uint4*)(cond_b + (size_t)r*128 + c0);
    cpo[0] = pack8(cv); cpo[1] = pack8(cv+8);
  }
}

// ---- shared GEMM helpers (XOR-swizzled LDS, 8-elem groups) ----
__device__ __forceinline__ void stage_A32(unsigned short* a_lds, const unsigned short* src,
                                          int row0, int tid) {
  const int r = tid >> 3, c0 = (tid & 7) << 4;
  const uint4* g = (const uint4*)(src + (size_t)(row0 + r) * 128 + c0);
  uint4 v0 = g[0], v1 = g[1];
  const int x = (r & 7) << 3;
  *(uint4*)&a_lds[r * 128 + (c0 ^ x)] = v0;
  *(uint4*)&a_lds[r * 128 + ((c0 + 8) ^ x)] = v1;
}
__device__ __forceinline__ void stage_W(unsigned short* w_lds, const unsigned short* src, int tid) {
  const int n = tid >> 1;
  const int kb = (tid & 1) << 6;
  const int x = (n & 7) << 3;
  const uint4* g = (const uint4*)(src + (size_t)n * 128 + kb);
#pragma unroll
  for (int i = 0; i < 8; ++i) {
    uint4 v = g[i];
    *(uint4*)&w_lds[n * 128 + ((kb + i * 8) ^ x)] = v;
  }
}
__device__ __forceinline__ void gemm32(const unsigned short* a_lds, const unsigned short* w_lds,
                                       int lm, int kg, int wv, f32x4 acc[2][2]) {
  const int xa = (lm & 7) << 3;
#pragma unroll
  for (int ks = 0; ks < 4; ++ks) {
    const int ko = ks * 32 + kg * 8;
    short8_t av[2], bv[2];
#pragma unroll
    for (int mi = 0; mi < 2; ++mi)
      av[mi] = *(const short8_t*)&a_lds[(mi * 16 + lm) * 128 + (ko ^ xa)];
#pragma unroll
    for (int ni = 0; ni < 2; ++ni) {
      const int n = (wv * 2 + ni) * 16 + lm;
      bv[ni] = *(const short8_t*)&w_lds[n * 128 + (ko ^ xa)];
    }
#pragma unroll
    for (int mi = 0; mi < 2; ++mi)
#pragma unroll
      for (int ni = 0; ni < 2; ++ni)
        acc[mi][ni] = __builtin_amdgcn_mfma_f32_16x16x32_bf16(av[mi], bv[ni], acc[mi][ni], 0, 0, 0);
  }
}

// ------------------------------------------------------------------
// K2a: 320 blocks = 64 row-tiles x {gate_q, skip_q, gate_k, skip_k, gs}.
// Depth-1: one A-stage, one W-stage, one GEMM, store.
// ------------------------------------------------------------------
__global__ __launch_bounds__(256) void gateskip_kernel(
    const unsigned short* __restrict__ wt_all, const unsigned short* __restrict__ sn_b,
    const unsigned short* __restrict__ cond_b, const float* __restrict__ bgs,
    float* __restrict__ gateq_f, float* __restrict__ skipq_f,
    float* __restrict__ gatek_f, float* __restrict__ skipk_f,
    unsigned short* __restrict__ gs_b)
{
  __shared__ unsigned short a_lds[32 * 128];
  __shared__ unsigned short w_lds[128 * 128];
  const int tid = threadIdx.x;
  const int br = blockIdx.x / 64;       // 0..4
  const int rt = blockIdx.x % 64;
  const int row0 = rt * 32;
  const int l = tid & 63, wv = tid >> 6;
  const int lm = l & 15, kg = l >> 4;
  const int wsel = (br == 4) ? 8 : br;
  stage_A32(a_lds, (br == 4) ? cond_b : sn_b, row0, tid);
  stage_W(w_lds, wt_all + (size_t)wsel * 16384, tid);
  __syncthreads();
  f32x4 acc[2][2] = {};
  gemm32(a_lds, w_lds, lm, kg, wv, acc);
  if (br == 4) {
    float bgv[2];
#pragma unroll
    for (int ni = 0; ni < 2; ++ni) bgv[ni] = bgs[(wv * 2 + ni) * 16 + lm];
#pragma unroll
    for (int mi = 0; mi < 2; ++mi)
#pragma unroll
      for (int ni = 0; ni < 2; ++ni)
#pragma unroll
        for (int r = 0; r < 4; ++r) {
          const int rl = mi * 16 + kg * 4 + r;
          const int n = (wv * 2 + ni) * 16 + lm;
          gs_b[(size_t)(row0 + rl) * 128 + n] = f2bu(sigm(acc[mi][ni][r] + bgv[ni]));
        }
    return;
  }
  float* dst = (br == 0) ? gateq_f : (br == 1) ? skipq_f : (br == 2) ? gatek_f : skipk_f;
#pragma unroll
  for (int mi = 0; mi < 2; ++mi)
#pragma unroll
    for (int ni = 0; ni < 2; ++ni)
#pragma unroll
      for (int r = 0; r < 4; ++r) {
        const int rl = mi * 16 + kg * 4 + r;
        const int n = (wv * 2 + ni) * 16 + lm;
        dst[(size_t)(row0 + rl) * 128 + n] = acc[mi][ni][r];
      }
}

// ------------------------------------------------------------------
// K2b: 256 blocks = 64 row-tiles x {q, g, k, v}. AdaLN combine fused into
// A-staging; V written pre-transposed [dim][token].
// ------------------------------------------------------------------
__global__ __launch_bounds__(256) void qkvg_kernel(
    const unsigned short* __restrict__ wt_all, const unsigned short* __restrict__ xn_b,
    const float* __restrict__ gateq_f, const float* __restrict__ skipq_f,
    const float* __restrict__ gatek_f, const float* __restrict__ skipk_f,
    const float* __restrict__ bgate_q, const float* __restrict__ bgate_k,
    const float* __restrict__ bq,
    unsigned short* __restrict__ q_b, unsigned short* __restrict__ k_b,
    unsigned short* __restrict__ vt_b, unsigned short* __restrict__ gsig_b)
{
  __shared__ unsigned short a_lds[32 * 128];
  __shared__ unsigned short w_lds[128 * 128];
  const int tid = threadIdx.x;
  const int br = blockIdx.x >> 6;       // 0:q 1:g 2:k 3:v
  const int rt = blockIdx.x & 63;
  const int row0 = rt * 32;
  const int l = tid & 63, wv = tid >> 6;
  const int lm = l & 15, kg = l >> 4;
  const bool useq = (br < 2);
  const float* gate_f = useq ? gateq_f : gatek_f;
  const float* skip_f = useq ? skipq_f : skipk_f;
  const float* bg = useq ? bgate_q : bgate_k;

  { // stage A = sigm(gate+bg)*xn + skip, swizzled bf16
    const int r = tid >> 3, c0 = (tid & 7) << 4;
    const size_t base = (size_t)(row0 + r) * 128 + c0;
    const float4* gp = (const float4*)(gate_f + base);
    const float4* sp = (const float4*)(skip_f + base);
    const float4* bp = (const float4*)(bg + c0);
    const uint4* xp = (const uint4*)(xn_b + base);
    uint4 xu0 = xp[0], xu1 = xp[1];
    unsigned short xs[16];
    __builtin_memcpy(xs, &xu0, 16); __builtin_memcpy(xs + 8, &xu1, 16);
    float av[16];
#pragma unroll
    for (int i = 0; i < 4; ++i) {
      float4 g4 = gp[i], s4 = sp[i], b4 = bp[i];
      av[4*i+0] = sigm(g4.x + b4.x) * bu2f(xs[4*i+0]) + s4.x;
      av[4*i+1] = sigm(g4.y + b4.y) * bu2f(xs[4*i+1]) + s4.y;
      av[4*i+2] = sigm(g4.z + b4.z) * bu2f(xs[4*i+2]) + s4.z;
      av[4*i+3] = sigm(g4.w + b4.w) * bu2f(xs[4*i+3]) + s4.w;
    }
    const int x = (r & 7) << 3;
    *(uint4*)&a_lds[r * 128 + (c0 ^ x)] = pack8(av);
    *(uint4*)&a_lds[r * 128 + ((c0 + 8) ^ x)] = pack8(av + 8);
  }
  const int wsel = (br == 0) ? 4 : (br == 1) ? 7 : (br == 2) ? 5 : 6;
  stage_W(w_lds, wt_all + (size_t)wsel * 16384, tid);
  __syncthreads();
  f32x4 acc[2][2] = {};
  gemm32(a_lds, w_lds, lm, kg, wv, acc);

  if (br == 3) {
    // v transposed: vt_b[n][token], ushort4 over 4 consecutive tokens
#pragma unroll
    for (int mi = 0; mi < 2; ++mi)
#pragma unroll
      for (int ni = 0; ni < 2; ++ni) {
        const int n = (wv * 2 + ni) * 16 + lm;
        const int tok0 = row0 + mi * 16 + kg * 4;
        ushort4 o;
        o.x = f2bu(acc[mi][ni][0]); o.y = f2bu(acc[mi][ni][1]);
        o.z = f2bu(acc[mi][ni][2]); o.w = f2bu(acc[mi][ni][3]);
        *(ushort4*)(vt_b + (size_t)n * NTOK + tok0) = o;
      }
    return;
  }
  const float scale = 0.17677669529663687f;
  float bqv[2] = {0.f, 0.f};
  if (br == 0) {
#pragma unroll
    for (int ni = 0; ni < 2; ++ni) bqv[ni] = bq[(wv * 2 + ni) * 16 + lm];
  }
  unsigned short* dst = (br == 0) ? q_b : (br == 1) ? gsig_b : k_b;
#pragma unroll
  for (int mi = 0; mi < 2; ++mi)
#pragma unroll
    for (int ni = 0; ni < 2; ++ni)
#pragma unroll
      for (int r = 0; r < 4; ++r) {
        const int rl = mi * 16 + kg * 4 + r;
        const int n = (wv * 2 + ni) * 16 + lm;
        float v = acc[mi][ni][r];
        if (br == 0) v = (v + bqv[ni]) * scale;
        else if (br == 1) v = sigm(v);
        dst[(size_t)(row0 + rl) * 128 + n] = f2bu(v);
      }
}

// ------------------------------------------------------------------
// K3: attention per (qblock, head). 256 blocks x 256 threads.
// V staged from pre-transposed vt_b (vector loads, no scatter).
// ------------------------------------------------------------------
__global__ __launch_bounds__(256) void attn_kernel(
    const unsigned short* __restrict__ q_b, const unsigned short* __restrict__ k_b,
    const unsigned short* __restrict__ vt_b, const unsigned short* __restrict__ gsig_b,
    const unsigned short* __restrict__ bias_h, unsigned short* __restrict__ o_b)
{
  __shared__ unsigned short k_lds[128 * 64];
  __shared__ unsigned short vt[32 * 128];
  __shared__ unsigned short p_lds[32 * 128];
  __shared__ unsigned short q_lds[32 * 64];
  __shared__ unsigned short bias_lds[32 * 136];
  __shared__ float mxlds[4][32];
  __shared__ float smlds[4][32];
  __shared__ f32x4 op[16][64];
  const int tid = threadIdx.x;
  const int h = blockIdx.x & 3, b = blockIdx.x >> 2;
  const int j0 = b * 32 - 48;
  const int l = tid & 63, wv = tid >> 6;
  const int lm = l & 15, kg = l >> 4;

  { // Q stage
    const int r = tid >> 3, c0 = (tid & 7) << 2;
    ushort4 v = *(const ushort4*)(q_b + (size_t)(b * 32 + r) * 128 + h * 32 + c0);
    *(ushort4*)&q_lds[r * 64 + (c0 ^ ((r & 7) << 3))] = v;
  }
  { // bias stage
    const int r = tid >> 3, c0 = (tid & 7) << 4;
    const uint4* g = (const uint4*)(bias_h + (size_t)h * (NTOK * 128) + (size_t)(b * 32 + r) * 128 + c0);
    uint4 v0 = g[0], v1 = g[1];
    *(uint4*)&bias_lds[r * 136 + c0] = v0;
    *(uint4*)&bias_lds[r * 136 + c0 + 8] = v1;
  }
  { // K stage
    const int jw = tid >> 1, cb = (tid & 1) << 4;
    const int j = j0 + jw;
    uint4 kv0 = {0,0,0,0}, kv1 = {0,0,0,0};
    if (j >= 0 && j < NTOK) {
      const uint4* gk = (const uint4*)(k_b + (size_t)j * 128 + h * 32 + cb);
      kv0 = gk[0]; kv1 = gk[1];
    }
    const int xk = (jw & 7) << 3;
    *(uint4*)&k_lds[jw * 64 + (cb ^ xk)] = kv0;
    *(uint4*)&k_lds[jw * 64 + ((cb + 8) ^ xk)] = kv1;
  }
  { // V stage from vt_b: 16-key chunks (window is 16-aligned)
    const int c = tid >> 3, koff = (tid & 7) << 4;
    const int j = j0 + koff;
    uint4 v0 = {0,0,0,0}, v1 = {0,0,0,0};
    if (j >= 0 && j + 15 < NTOK) {
      const uint4* gv = (const uint4*)(vt_b + (size_t)(h * 32 + c) * NTOK + j);
      v0 = gv[0]; v1 = gv[1];
    }
    const int xc = (c & 7) << 3;
    *(uint4*)&vt[c * 128 + (koff ^ xc)] = v0;
    *(uint4*)&vt[c * 128 + ((koff + 8) ^ xc)] = v1;
  }
  __syncthreads();

  // QK^T
  f32x4 sc[2][2] = {};
  {
    const int xa = (lm & 7) << 3;
    short8_t aq[2], bk[2];
#pragma unroll
    for (int mi = 0; mi < 2; ++mi)
      aq[mi] = *(const short8_t*)&q_lds[(mi * 16 + lm) * 64 + ((kg * 8) ^ xa)];
#pragma unroll
    for (int ni = 0; ni < 2; ++ni) {
      const int key = (wv * 2 + ni) * 16 + lm;
      bk[ni] = *(const short8_t*)&k_lds[key * 64 + ((kg * 8) ^ ((key & 7) << 3))];
    }
#pragma unroll
    for (int mi = 0; mi < 2; ++mi)
#pragma unroll
      for (int ni = 0; ni < 2; ++ni)
        sc[mi][ni] = __builtin_amdgcn_mfma_f32_16x16x32_bf16(aq[mi], bk[ni], sc[mi][ni], 0, 0, 0);
  }
  float sv[2][2][4];
#pragma unroll
  for (int mi = 0; mi < 2; ++mi)
#pragma unroll
    for (int ni = 0; ni < 2; ++ni)
#pragma unroll
      for (int r = 0; r < 4; ++r) {
        const int q = mi * 16 + kg * 4 + r;
        const int key = (wv * 2 + ni) * 16 + lm;
        sv[mi][ni][r] = sc[mi][ni][r] + bu2f(bias_lds[q * 136 + key]);
      }
#pragma unroll
  for (int mi = 0; mi < 2; ++mi)
#pragma unroll
    for (int r = 0; r < 4; ++r) {
      float m0 = fmaxf(sv[mi][0][r], sv[mi][1][r]);
#pragma unroll
      for (int msk = 1; msk < 16; msk <<= 1) m0 = fmaxf(m0, __shfl_xor(m0, msk));
      if (lm == 0) mxlds[wv][mi * 16 + kg * 4 + r] = m0;
    }
  __syncthreads();
#pragma unroll
  for (int mi = 0; mi < 2; ++mi)
#pragma unroll
    for (int r = 0; r < 4; ++r) {
      const int q = mi * 16 + kg * 4 + r;
      const float m = fmaxf(fmaxf(mxlds[0][q], mxlds[1][q]), fmaxf(mxlds[2][q], mxlds[3][q]));
      float s = 0.f;
#pragma unroll
      for (int ni = 0; ni < 2; ++ni) {
        const float e = __expf(sv[mi][ni][r] - m);
        const int key = (wv * 2 + ni) * 16 + lm;
        p_lds[q * 128 + ((key & 7) | ((key & 120) ^ ((q & 7) << 3)))] = f2bu(e);
        s += e;
      }
#pragma unroll
      for (int msk = 1; msk < 16; msk <<= 1) s += __shfl_xor(s, msk);
      if (lm == 0) smlds[wv][q] = s;
    }
  // PV: wave-local 32 keys
  f32x4 oacc[2][2] = {};
  {
    const int key0 = wv * 32 + kg * 8;
    short8_t pa[2], vbf[2];
#pragma unroll
    for (int mi = 0; mi < 2; ++mi) {
      const int q = mi * 16 + lm;
      pa[mi] = *(const short8_t*)&p_lds[q * 128 + (key0 ^ ((q & 7) << 3))];
    }
#pragma unroll
    for (int ct = 0; ct < 2; ++ct) {
      const int c = ct * 16 + lm;
      vbf[ct] = *(const short8_t*)&vt[c * 128 + (key0 ^ ((c & 7) << 3))];
    }
#pragma unroll
    for (int mi = 0; mi < 2; ++mi)
#pragma unroll
      for (int ct = 0; ct < 2; ++ct)
        oacc[mi][ct] = __builtin_amdgcn_mfma_f32_16x16x32_bf16(pa[mi], vbf[ct], oacc[mi][ct], 0, 0, 0);
  }
#pragma unroll
  for (int mi = 0; mi < 2; ++mi)
#pragma unroll
    for (int ct = 0; ct < 2; ++ct)
      op[wv * 4 + mi * 2 + ct][l] = oacc[mi][ct];
  __syncthreads();
  { // reduce partials + gate + store
    const int q = tid >> 3, c0 = (tid & 7) << 2;
    const int mt = q >> 4, g = (q >> 2) & 3, r = q & 3;
    const float tot = smlds[0][q] + smlds[1][q] + smlds[2][q] + smlds[3][q];
    const float inv = 1.f / tot;
    ushort4 gg = *(const ushort4*)(gsig_b + (size_t)(b * 32 + q) * 128 + h * 32 + c0);
    unsigned short gga[4] = {gg.x, gg.y, gg.z, gg.w};
    unsigned short outa[4];
#pragma unroll
    for (int i2 = 0; i2 < 4; ++i2) {
      const int c = c0 + i2;
      const int ct = c >> 4, lane = g * 16 + (c & 15);
      float s = 0.f;
#pragma unroll
      for (int w2 = 0; w2 < 4; ++w2)
        s += ((const float*)&op[w2 * 4 + mt * 2 + ct][lane])[r];
      outa[i2] = f2bu(s * inv * bu2f(gga[i2]));
    }
    ushort4 ov; ov.x = outa[0]; ov.y = outa[1]; ov.z = outa[2]; ov.w = outa[3];
    *(ushort4*)(o_b + (size_t)(b * 32 + q) * 128 + h * 32 + c0) = ov;
  }
}

// ------------------------------------------------------------------
// K4: out = gs * (o @ Wo), f32 store. 128 blocks x 16 rows.
// ------------------------------------------------------------------
__global__ __launch_bounds__(256) void out_kernel(
    const unsigned short* __restrict__ wt_all, const unsigned short* __restrict__ o_b,
    const unsigned short* __restrict__ gs_b, float* __restrict__ out)
{
  __shared__ unsigned short a_lds[16 * 128];
  __shared__ unsigned short w_lds[128 * 128];
  const int tid = threadIdx.x;
  const int row0 = blockIdx.x * 16;
  const int l = tid & 63, wv = tid >> 6;
  const int lm = l & 15, kg = l >> 4;
  {
    const int r = tid >> 4, c0 = (tid & 15) << 3;
    uint4 v = *(const uint4*)(o_b + (size_t)(row0 + r) * 128 + c0);
    *(uint4*)&a_lds[r * 128 + (c0 ^ ((r & 7) << 3))] = v;
  }
  stage_W(w_lds, wt_all + (size_t)9 * 16384, tid);
  __syncthreads();
  f32x4 acc[2] = {};
  const int xa = (lm & 7) << 3;
#pragma unroll
  for (int ks = 0; ks < 4; ++ks) {
    const int ko = ks * 32 + kg * 8;
    short8_t av = *(const short8_t*)&a_lds[lm * 128 + (ko ^ xa)];
#pragma unroll
    for (int ni = 0; ni < 2; ++ni) {
      const int n = (wv * 2 + ni) * 16 + lm;
      short8_t bv = *(const short8_t*)&w_lds[n * 128 + (ko ^ xa)];
      acc[ni] = __builtin_amdgcn_mfma_f32_16x16x32_bf16(av, bv, acc[ni], 0, 0, 0);
    }
  }
#pragma unroll
  for (int ni = 0; ni < 2; ++ni)
#pragma unroll
    for (int r = 0; r < 4; ++r) {
      const int rl = kg * 4 + r;
      const int n = (wv * 2 + ni) * 16 + lm;
      const float gsv = bu2f(gs_b[(size_t)(row0 + rl) * 128 + n]);
      out[(size_t)(row0 + rl) * 128 + n] = acc[ni][r] * gsv;
    }
}

extern "C" void kernel_launch(void* const* d_in, const int* in_sizes, int n_in,
                              void* d_out, int out_size, void* d_ws, size_t ws_size,
                              hipStream_t stream) {
  const float* act     = (const float*)d_in[0];
  const float* pair    = (const float*)d_in[1];
  const float* cond    = (const float*)d_in[2];
  const float* lns_q   = (const float*)d_in[4];
  const float* Wgate_q = (const float*)d_in[5];
  const float* bgate_q = (const float*)d_in[6];
  const float* Wskip_q = (const float*)d_in[7];
  const float* lns_k   = (const float*)d_in[8];
  const float* Wgate_k = (const float*)d_in[9];
  const float* bgate_k = (const float*)d_in[10];
  const float* Wskip_k = (const float*)d_in[11];
  const float* lnz_w   = (const float*)d_in[12];
  const float* Wq      = (const float*)d_in[13];
  const float* bq      = (const float*)d_in[14];
  const float* Wk      = (const float*)d_in[15];
  const float* Wv      = (const float*)d_in[16];
  const float* Wg      = (const float*)d_in[17];
  const float* Wb      = (const float*)d_in[18];
  const float* Wo      = (const float*)d_in[19];
  const float* Wgs     = (const float*)d_in[20];
  const float* bgs     = (const float*)d_in[21];
  float* out           = (float*)d_out;

  unsigned short* ws = (unsigned short*)d_ws;
  unsigned short* wt_all = ws;                      // 10*16384
  unsigned short* xn_b   = ws + 163840;
  unsigned short* sn_b   = ws + 425984;
  unsigned short* cond_b = ws + 688128;
  unsigned short* q_b    = ws + 950272;
  unsigned short* k_b    = ws + 1212416;
  unsigned short* vt_b   = ws + 1474560;            // [128 dims][2048 tokens]
  unsigned short* gsig_b = ws + 1736704;
  unsigned short* gs_b   = ws + 1998848;
  unsigned short* o_b    = ws + 2260992;
  unsigned short* bias_h = ws + 2523136;            // 4*2048*128
  float* f32ws   = (float*)(ws + 3571712);
  float* gateq_f = f32ws;                           // 2048*128 each
  float* skipq_f = f32ws + 262144;
  float* gatek_f = f32ws + 524288;
  float* skipk_f = f32ws + 786432;

  hipLaunchKernelGGL(prep_bias_kernel, dim3(1248), dim3(256), 0, stream,
                     act, cond, lns_q, lns_k,
                     Wgate_q, Wskip_q, Wgate_k, Wskip_k,
                     Wq, Wk, Wv, Wg, Wgs, Wo,
                     pair, lnz_w, Wb,
                     wt_all, xn_b, sn_b, cond_b, bias_h);
  hipLaunchKernelGGL(gateskip_kernel, dim3(320), dim3(256), 0, stream,
                     wt_all, sn_b, cond_b, bgs,
                     gateq_f, skipq_f, gatek_f, skipk_f, gs_b);
  hipLaunchKernelGGL(qkvg_kernel, dim3(256), dim3(256), 0, stream,
                     wt_all, xn_b, gateq_f, skipq_f, gatek_f, skipk_f,
                     bgate_q, bgate_k, bq,
                     q_b, k_b, vt_b, gsig_b);
  hipLaunchKernelGGL(attn_kernel, dim3(256), dim3(256), 0, stream,
                     q_b, k_b, vt_b, gsig_b, bias_h, o_b);
  hipLaunchKernelGGL(out_kernel, dim3(128), dim3(256), 0, stream,
                     wt_all, o_b, gs_b, out);
}